// Round 12
// baseline (274.525 us; speedup 1.0000x reference)
//
#include <hip/hip_runtime.h>

using bf16   = __bf16;
using bf16x8 = __attribute__((ext_vector_type(8))) __bf16;
using f32x4  = __attribute__((ext_vector_type(4))) float;
using u32x4  = __attribute__((ext_vector_type(4))) unsigned;

// B=2 T=2048 D=2048 H=32 KVH=8 HD=64 GROUPS=4 ; M=B*T=4096 ; NQKV=3072
#define T_SEQ 2048
#define NQKV 3072

__device__ __forceinline__ void async_cp16(const bf16* g, bf16* l) {
  __builtin_amdgcn_global_load_lds((__attribute__((address_space(1))) void*)(void*)g,
                                   (__attribute__((address_space(3))) void*)l, 16, 0, 0);
}

// ------------- fused prep: cvt(x) | wq^T | wkv^T | wo^T as z-slices -------------
__global__ __launch_bounds__(256) void prep_kernel(
    const float* __restrict__ x, bf16* __restrict__ xbf,
    const float* __restrict__ wq, const float* __restrict__ wkv,
    const float* __restrict__ wo, bf16* __restrict__ w1,
    bf16* __restrict__ woT) {
  const int z = blockIdx.z;
  if (z == 0) {                 // fp32 -> bf16 convert of x (64x64 blocks = 4096)
    long i = (((long)blockIdx.y * 64 + blockIdx.x) * 256 + threadIdx.x) * 8;
    float4 a = *(const float4*)(x + i);
    float4 c = *(const float4*)(x + i + 4);
    bf16x8 v;
    v[0] = (bf16)a.x; v[1] = (bf16)a.y; v[2] = (bf16)a.z; v[3] = (bf16)a.w;
    v[4] = (bf16)c.x; v[5] = (bf16)c.y; v[6] = (bf16)c.z; v[7] = (bf16)c.w;
    *(bf16x8*)(xbf + i) = v;
    return;
  }
  const float* in; bf16* out; int R, C;
  if (z == 1)      { in = wq;  out = w1;                R = 2048; C = 2048; }
  else if (z == 2) { if (blockIdx.x >= 32) return;
                     in = wkv; out = w1 + 2048L * 2048; R = 2048; C = 1024; }
  else             { in = wo;  out = woT;               R = 2048; C = 2048; }
  __shared__ float tile[32][33];
  const int tc = blockIdx.x * 32;
  const int tr = blockIdx.y * 32;
  const int t = threadIdx.x;
  const int lr = t >> 5;
  const int lc = t & 31;
#pragma unroll
  for (int i = 0; i < 4; ++i)
    tile[lr + i * 8][lc] = in[(size_t)(tr + lr + i * 8) * C + tc + lc];
  __syncthreads();
#pragma unroll
  for (int i = 0; i < 4; ++i)
    out[(size_t)(tc + lr + i * 8) * R + tr + lc] = (bf16)tile[lc][lr + i * 8];
}

// ------------- transpose + convert (standalone, fallback paths) ----------------
__global__ __launch_bounds__(256) void transpose_cvt(const float* __restrict__ in,
                                                     bf16* __restrict__ out,
                                                     int R, int C) {
  __shared__ float tile[32][33];
  const int tc = blockIdx.x * 32;
  const int tr = blockIdx.y * 32;
  const int t = threadIdx.x;
  const int lr = t >> 5;
  const int lc = t & 31;
#pragma unroll
  for (int i = 0; i < 4; ++i)
    tile[lr + i * 8][lc] = in[(size_t)(tr + lr + i * 8) * C + tc + lc];
  __syncthreads();
#pragma unroll
  for (int i = 0; i < 4; ++i)
    out[(size_t)(tc + lr + i * 8) * R + tr + lc] = (bf16)tile[lc][lr + i * 8];
}

// ------------- bf16 transpose of the V block of qkv (fallback path) -------------
__global__ __launch_bounds__(256) void transpose_v(const bf16* __restrict__ in,
                                                   bf16* __restrict__ out) {
  __shared__ bf16 tile[32][33];
  const int c0 = blockIdx.x * 32;   // 0..480
  const int r0 = blockIdx.y * 32;   // 0..4064
  const int t = threadIdx.x;
  const int lr = t >> 5;
  const int lc = t & 31;
#pragma unroll
  for (int i = 0; i < 4; ++i)
    tile[lr + i * 8][lc] = in[(size_t)(r0 + lr + i * 8) * NQKV + 2560 + c0 + lc];
  __syncthreads();
#pragma unroll
  for (int i = 0; i < 4; ++i) {
    int c = c0 + lr + i * 8;
    int r = r0 + lc;
    out[(size_t)((r >> 11) * 512 + c) * 2048 + (r & 2047)] = tile[lc][lr + i * 8];
  }
}

// ------------- 8-phase 256^2 GEMM (faithful m201-template port, r19) ------------
// r13's failures fixed: (1) W-A-R race - stage placement now DERIVED from a
// read/write ledger at 64-row-QUARTER granularity; (2) sched_barrier(0) pins
// removed (m141). Schedule per K-tile t (4 phases = quadrants (ks,mtop)):
//   boundary: vmcnt(2) [only ph3's 2 stages float] ; s_barrier
//   ph0 (ks0,m0): 4A+4B ds_read | stage A-q1,q3(t+1)->nxt | bar | lgkm0 |
//                 prio1 16xMFMA prio0 | bar
//   ph1 (ks0,m1): 4A ds_read (B reused) | stage B-q0,q1(t+1)->nxt | ...
//   ph2 (ks1,m0): 4A+4B | stage B-q2,q3(t+1)->nxt | ...
//   ph3 (ks1,m1): 4A | stage A-q0,q2(t+2)->cur | ... (no trailing barrier;
//                 merged with next boundary)
// Ledger: nxt-stages overwrite tile t-1 (dead since its ph3 + barriers);
// cur-stage A-q0,q2(t+2) overwrites A-q0,q2(t), last ds_read at ph2, separated
// by ph2's end-barrier. Per-wave vmcnt + barrier => all waves' stages landed.
// 8 waves (2M x 4N), BM=BN=256, BK=64; per-wave 128x64 out; 16 MFMA/phase.
// LDS 128KB -> 1 block/CU; (512,2) caps regs at 256 (~190 live).
// Spill tripwire: WRITE_SIZE; race tripwire: absmax.
template <int KDIM, bool OUT_BF16, bool V_SPLIT>
__global__ __launch_bounds__(512, 2)
void gemm8p_kernel(const bf16* __restrict__ A, const bf16* __restrict__ Bt,
                   void* __restrict__ Cout, bf16* __restrict__ vTout, int Ndim) {
  constexpr int NT = KDIM / 64;
  __shared__ __attribute__((aligned(16))) bf16 As[2][256 * 64];
  __shared__ __attribute__((aligned(16))) bf16 Bs[2][256 * 64];

  const int tid  = threadIdx.x;
  const int lane = tid & 63;
  const int wave = tid >> 6;
  const int l16  = lane & 15;
  const int q4   = lane >> 4;
  const int wm   = (wave >> 2) * 128;
  const int wn   = (wave & 3) * 64;

  // XCD swizzle (bijective: nwg % 8 == 0 for both call sites)
  const int nwg = gridDim.x * gridDim.y;
  int wg = blockIdx.y * gridDim.x + blockIdx.x;
  wg = (wg & 7) * (nwg >> 3) + (wg >> 3);
  const long m0 = (long)(wg / gridDim.x) * 256;
  const long n0 = (long)(wg % gridDim.x) * 256;

  const bf16* Ag = A + m0 * (long)KDIM;
  const bf16* Bg = Bt + n0 * (long)KDIM;

  f32x4 acc[8][4] = {};   // [mtop*4+mt][nt]

  // stage one 64-row quarter (1 x global_load_lds / thread = 8KB)
  auto stageAq = [&](int buf, int kt, int q) {
    const long k0 = (long)kt * 64;
    int row = q * 64 + (tid >> 3);
    int ch  = (tid & 7) ^ (row & 7);                 // swizzled global chunk
    async_cp16(Ag + (long)row * KDIM + k0 + ch * 8,
               &As[buf][row * 64 + (tid & 7) * 8]);  // linear LDS slot
  };
  auto stageBq = [&](int buf, int kt, int q) {
    const long k0 = (long)kt * 64;
    int row = q * 64 + (tid >> 3);
    int ch  = (tid & 7) ^ (row & 7);
    async_cp16(Bg + (long)row * KDIM + k0 + ch * 8,
               &Bs[buf][row * 64 + (tid & 7) * 8]);
  };

  // prologue: tile 0 complete + A-q0,q2 of tile 1 (the "(t-1).ph3" invariant)
#pragma unroll
  for (int q = 0; q < 4; ++q) stageAq(0, 0, q);
#pragma unroll
  for (int q = 0; q < 4; ++q) stageBq(0, 0, q);
  stageAq(1, 1, 0);
  stageAq(1, 1, 2);

  bf16x8 aF[4], bF[4];

  for (int t = 0; t < NT; ++t) {
    const int cur = t & 1, nxt = cur ^ 1;
    asm volatile("s_waitcnt vmcnt(2)" ::: "memory");
    __builtin_amdgcn_s_barrier();

    // ---- ph0: ks=0, mtop=0 ----
#pragma unroll
    for (int mt = 0; mt < 4; ++mt) {
      int row = wm + mt * 16 + l16;
      aF[mt] = *(const bf16x8*)&As[cur][row * 64 + (q4 ^ (row & 7)) * 8];
    }
#pragma unroll
    for (int nt = 0; nt < 4; ++nt) {
      int row = wn + nt * 16 + l16;
      bF[nt] = *(const bf16x8*)&Bs[cur][row * 64 + (q4 ^ (row & 7)) * 8];
    }
    if (t + 1 < NT) { stageAq(nxt, t + 1, 1); stageAq(nxt, t + 1, 3); }
    __builtin_amdgcn_s_barrier();
    asm volatile("s_waitcnt lgkmcnt(0)" ::: "memory");
    __builtin_amdgcn_s_setprio(1);
#pragma unroll
    for (int mt = 0; mt < 4; ++mt)
#pragma unroll
      for (int nt = 0; nt < 4; ++nt)
        acc[mt][nt] = __builtin_amdgcn_mfma_f32_16x16x32_bf16(aF[mt], bF[nt],
                                                              acc[mt][nt], 0, 0, 0);
    __builtin_amdgcn_s_setprio(0);
    __builtin_amdgcn_s_barrier();

    // ---- ph1: ks=0, mtop=1 (B-frags reused) ----
#pragma unroll
    for (int mt = 0; mt < 4; ++mt) {
      int row = wm + 64 + mt * 16 + l16;
      aF[mt] = *(const bf16x8*)&As[cur][row * 64 + (q4 ^ (row & 7)) * 8];
    }
    if (t + 1 < NT) { stageBq(nxt, t + 1, 0); stageBq(nxt, t + 1, 1); }
    __builtin_amdgcn_s_barrier();
    asm volatile("s_waitcnt lgkmcnt(0)" ::: "memory");
    __builtin_amdgcn_s_setprio(1);
#pragma unroll
    for (int mt = 0; mt < 4; ++mt)
#pragma unroll
      for (int nt = 0; nt < 4; ++nt)
        acc[4 + mt][nt] = __builtin_amdgcn_mfma_f32_16x16x32_bf16(aF[mt], bF[nt],
                                                                  acc[4 + mt][nt], 0, 0, 0);
    __builtin_amdgcn_s_setprio(0);
    __builtin_amdgcn_s_barrier();

    // ---- ph2: ks=1, mtop=0 ----
#pragma unroll
    for (int mt = 0; mt < 4; ++mt) {
      int row = wm + mt * 16 + l16;
      aF[mt] = *(const bf16x8*)&As[cur][row * 64 + ((4 + q4) ^ (row & 7)) * 8];
    }
#pragma unroll
    for (int nt = 0; nt < 4; ++nt) {
      int row = wn + nt * 16 + l16;
      bF[nt] = *(const bf16x8*)&Bs[cur][row * 64 + ((4 + q4) ^ (row & 7)) * 8];
    }
    if (t + 1 < NT) { stageBq(nxt, t + 1, 2); stageBq(nxt, t + 1, 3); }
    __builtin_amdgcn_s_barrier();
    asm volatile("s_waitcnt lgkmcnt(0)" ::: "memory");
    __builtin_amdgcn_s_setprio(1);
#pragma unroll
    for (int mt = 0; mt < 4; ++mt)
#pragma unroll
      for (int nt = 0; nt < 4; ++nt)
        acc[mt][nt] = __builtin_amdgcn_mfma_f32_16x16x32_bf16(aF[mt], bF[nt],
                                                              acc[mt][nt], 0, 0, 0);
    __builtin_amdgcn_s_setprio(0);
    __builtin_amdgcn_s_barrier();   // all A-q0,q2(cur) reads complete after this

    // ---- ph3: ks=1, mtop=1 ----
#pragma unroll
    for (int mt = 0; mt < 4; ++mt) {
      int row = wm + 64 + mt * 16 + l16;
      aF[mt] = *(const bf16x8*)&As[cur][row * 64 + ((4 + q4) ^ (row & 7)) * 8];
    }
    if (t + 2 < NT) { stageAq(cur, t + 2, 0); stageAq(cur, t + 2, 2); }
    __builtin_amdgcn_s_barrier();
    asm volatile("s_waitcnt lgkmcnt(0)" ::: "memory");
    __builtin_amdgcn_s_setprio(1);
#pragma unroll
    for (int mt = 0; mt < 4; ++mt)
#pragma unroll
      for (int nt = 0; nt < 4; ++nt)
        acc[4 + mt][nt] = __builtin_amdgcn_mfma_f32_16x16x32_bf16(aF[mt], bF[nt],
                                                                  acc[4 + mt][nt], 0, 0, 0);
    __builtin_amdgcn_s_setprio(0);
    // trailing barrier merged with next iteration's boundary barrier
  }

  // epilogue
#pragma unroll
  for (int idx = 0; idx < 8; ++idx) {
    const int mtop = idx >> 2, mt = idx & 3;
#pragma unroll
    for (int nt = 0; nt < 4; ++nt)
#pragma unroll
      for (int r = 0; r < 4; ++r) {
        long row = m0 + wm + mtop * 64 + mt * 16 + q4 * 4 + r;
        long col = n0 + wn + nt * 16 + l16;
        float v = acc[idx][nt][r];
        if (V_SPLIT && n0 >= 2560) {
          long c = col - 2560;
          vTout[((row >> 11) * 512 + c) * 2048 + (row & 2047)] = (bf16)v;
        } else if constexpr (OUT_BF16) {
          ((bf16*)Cout)[row * Ndim + col] = (bf16)v;
        } else {
          ((float*)Cout)[row * Ndim + col] = v;
        }
      }
  }
}

// ------------- GEMM (m97 structure, proven; used for gemm2 + fallback) ----------
template <bool OUT_BF16, bool V_SPLIT>
__global__ __launch_bounds__(256, 4)
void gemm_kernel(const bf16* __restrict__ A, const bf16* __restrict__ Bt,
                 void* __restrict__ Cout, bf16* __restrict__ vTout,
                 int Kdim, int Ndim) {
  __shared__ __attribute__((aligned(16))) bf16 As[128 * 64];
  __shared__ __attribute__((aligned(16))) bf16 Bs[128 * 64];
  const int tid  = threadIdx.x;
  const int lane = tid & 63;
  const int wave = tid >> 6;
  const int l16  = lane & 15;
  const int q4   = lane >> 4;

  const int nwg = gridDim.x * gridDim.y;
  int wg = blockIdx.y * gridDim.x + blockIdx.x;
  if ((nwg & 7) == 0) wg = (wg & 7) * (nwg >> 3) + (wg >> 3);
  const long m0 = (long)(wg / gridDim.x) * 128;
  const long n0 = (long)(wg % gridDim.x) * 128;

  const int wm = (wave >> 1) * 64;
  const int wn = (wave & 1) * 64;

  f32x4 acc[4][4] = {};

  for (int k0 = 0; k0 < Kdim; k0 += 64) {
    __syncthreads();
#pragma unroll
    for (int rr = 0; rr < 4; ++rr) {
      int ci  = rr * 256 + tid;
      int row = ci >> 3;
      int chp = ci & 7;
      int ch  = chp ^ (row & 7);
      async_cp16(A + (m0 + row) * (long)Kdim + k0 + ch * 8, &As[ci * 8]);
      async_cp16(Bt + (n0 + row) * (long)Kdim + k0 + ch * 8, &Bs[ci * 8]);
    }
    __syncthreads();
#pragma unroll
    for (int ks = 0; ks < 2; ++ks) {
      bf16x8 af[4], bfr[4];
#pragma unroll
      for (int mt = 0; mt < 4; ++mt) {
        int row = wm + mt * 16 + l16;
        int chp = (ks * 4 + q4) ^ (row & 7);
        af[mt] = *(const bf16x8*)&As[row * 64 + chp * 8];
      }
#pragma unroll
      for (int nt = 0; nt < 4; ++nt) {
        int row = wn + nt * 16 + l16;
        int chp = (ks * 4 + q4) ^ (row & 7);
        bfr[nt] = *(const bf16x8*)&Bs[row * 64 + chp * 8];
      }
#pragma unroll
      for (int mt = 0; mt < 4; ++mt)
#pragma unroll
        for (int nt = 0; nt < 4; ++nt)
          acc[mt][nt] = __builtin_amdgcn_mfma_f32_16x16x32_bf16(af[mt], bfr[nt],
                                                                acc[mt][nt], 0, 0, 0);
    }
  }

  if constexpr (V_SPLIT) {
    if (n0 >= 2560) {
#pragma unroll
      for (int mt = 0; mt < 4; ++mt)
#pragma unroll
        for (int nt = 0; nt < 4; ++nt)
#pragma unroll
          for (int r = 0; r < 4; ++r) {
            long row = m0 + wm + mt * 16 + q4 * 4 + r;
            long c   = n0 + wn + nt * 16 + l16 - 2560;
            vTout[((row >> 11) * 512 + c) * 2048 + (row & 2047)] =
                (bf16)acc[mt][nt][r];
          }
      return;
    }
  }
#pragma unroll
  for (int mt = 0; mt < 4; ++mt)
#pragma unroll
    for (int nt = 0; nt < 4; ++nt)
#pragma unroll
      for (int r = 0; r < 4; ++r) {
        long row = m0 + wm + mt * 16 + q4 * 4 + r;
        long col = n0 + wn + nt * 16 + l16;
        float v = acc[mt][nt][r];
        if constexpr (OUT_BF16)
          ((bf16*)Cout)[row * Ndim + col] = (bf16)v;
        else
          ((float*)Cout)[row * Ndim + col] = v;
      }
}

// ------------- causal GQA flash attention (r8-exact, the 245.2us config) --------
__global__ __launch_bounds__(256, 3)
void attn_kernel(const bf16* __restrict__ qkv, const bf16* __restrict__ vT,
                 bf16* __restrict__ outb) {
  __shared__ __attribute__((aligned(16))) bf16 Ks[64 * 64];   // swizzled chunks
  __shared__ __attribute__((aligned(16))) bf16 Vs[64 * 64];   // V^T tile, swizzled

  const int tid  = threadIdx.x;
  const int lane = tid & 63;
  const int wave = tid >> 6;
  const int l16  = lane & 15;
  const int q4   = lane >> 4;

  const int bid = blockIdx.x;
  const int qt  = 15 - (bid >> 6);   // heavy q-tiles dispatched first
  const int bh  = bid & 63;
  const int b   = bh >> 5;
  const int h   = bh & 31;
  const int kvh = h >> 2;
  const long rowbase = (long)b * T_SEQ;

  const int qrow0 = qt * 128;
  const int wq0   = qrow0 + wave * 32;
  const float cexp = 0.125f * 1.4426950408889634f;  // scale * log2(e), folded into Q

  bf16x8 aq[2][2];
#pragma unroll
  for (int mt = 0; mt < 2; ++mt)
#pragma unroll
    for (int ks = 0; ks < 2; ++ks) {
      bf16x8 v = *(const bf16x8*)(qkv +
          (rowbase + wq0 + mt * 16 + l16) * (long)NQKV + h * 64 + ks * 32 + q4 * 8);
#pragma unroll
      for (int i = 0; i < 8; ++i) v[i] = (bf16)((float)v[i] * cexp);
      aq[mt][ks] = v;
    }

  bf16x8 ones_f;
#pragma unroll
  for (int i = 0; i < 8; ++i) ones_f[i] = (l16 == 0) ? (bf16)1.0f : (bf16)0.0f;

  f32x4 o[2][4] = {};
  f32x4 o_l[2] = {};

  const bf16* kbase = qkv + rowbase * (long)NQKV + 2048 + kvh * 64;
  const bf16* vbase = vT + ((long)b * 512 + kvh * 64) * 2048;

  const int ntiles = (qrow0 + 128) >> 6;

  bf16x8 kr[2], vr[2];
#pragma unroll
  for (int h2 = 0; h2 < 2; ++h2) {
    int ci = h2 * 256 + tid, row = ci >> 3, ch = (ci & 7) ^ (row & 7);
    kr[h2] = *(const bf16x8*)(kbase + (long)row * NQKV + ch * 8);
    vr[h2] = *(const bf16x8*)(vbase + (long)row * 2048 + ch * 8);
  }

  for (int t = 0; t < ntiles; ++t) {
    const int j0 = t * 64;
    __syncthreads();
#pragma unroll
    for (int h2 = 0; h2 < 2; ++h2) {
      int ci = h2 * 256 + tid;
      *(bf16x8*)&Ks[ci * 8] = kr[h2];
      *(bf16x8*)&Vs[ci * 8] = vr[h2];
    }
    __syncthreads();
    if (t + 1 < ntiles) {
      const int jn = j0 + 64;
#pragma unroll
      for (int h2 = 0; h2 < 2; ++h2) {
        int ci = h2 * 256 + tid, row = ci >> 3, ch = (ci & 7) ^ (row & 7);
        kr[h2] = *(const bf16x8*)(kbase + (long)(jn + row) * NQKV + ch * 8);
        vr[h2] = *(const bf16x8*)(vbase + (long)row * 2048 + jn + ch * 8);
      }
    }
    if (j0 > wq0 + 31) continue;

    f32x4 s[2][4] = {};
#pragma unroll
    for (int ks = 0; ks < 2; ++ks) {
      bf16x8 bk[4];
#pragma unroll
      for (int nt = 0; nt < 4; ++nt) {
        int row  = nt * 16 + l16;
        int slot = (ks * 4 + q4) ^ (row & 7);
        bk[nt] = *(const bf16x8*)&Ks[row * 64 + slot * 8];
      }
#pragma unroll
      for (int mt = 0; mt < 2; ++mt)
#pragma unroll
        for (int nt = 0; nt < 4; ++nt)
          s[mt][nt] = __builtin_amdgcn_mfma_f32_16x16x32_bf16(bk[nt], aq[mt][ks],
                                                              s[mt][nt], 0, 0, 0);
    }

    if (j0 + 63 > wq0) {
#pragma unroll
      for (int mt = 0; mt < 2; ++mt)
#pragma unroll
        for (int nt = 0; nt < 4; ++nt)
#pragma unroll
          for (int r = 0; r < 4; ++r) {
            int rg = wq0 + mt * 16 + l16;
            int cg = j0 + nt * 16 + q4 * 4 + r;
            if (cg > rg) s[mt][nt][r] = -__builtin_inff();
          }
    }

    bf16x8 ap[2][2];
#pragma unroll
    for (int mt = 0; mt < 2; ++mt) {
      unsigned pk0, pk1, pk2, pk3, pk4, pk5, pk6, pk7;
      {
        float p0 = __builtin_amdgcn_exp2f(s[mt][0][0]);
        float p1 = __builtin_amdgcn_exp2f(s[mt][0][1]);
        float p2 = __builtin_amdgcn_exp2f(s[mt][0][2]);
        float p3 = __builtin_amdgcn_exp2f(s[mt][0][3]);
        asm("v_cvt_pk_bf16_f32 %0, %1, %2" : "=v"(pk0) : "v"(p0), "v"(p1));
        asm("v_cvt_pk_bf16_f32 %0, %1, %2" : "=v"(pk1) : "v"(p2), "v"(p3));
      }
      {
        float p0 = __builtin_amdgcn_exp2f(s[mt][1][0]);
        float p1 = __builtin_amdgcn_exp2f(s[mt][1][1]);
        float p2 = __builtin_amdgcn_exp2f(s[mt][1][2]);
        float p3 = __builtin_amdgcn_exp2f(s[mt][1][3]);
        asm("v_cvt_pk_bf16_f32 %0, %1, %2" : "=v"(pk2) : "v"(p0), "v"(p1));
        asm("v_cvt_pk_bf16_f32 %0, %1, %2" : "=v"(pk3) : "v"(p2), "v"(p3));
      }
      {
        float p0 = __builtin_amdgcn_exp2f(s[mt][2][0]);
        float p1 = __builtin_amdgcn_exp2f(s[mt][2][1]);
        float p2 = __builtin_amdgcn_exp2f(s[mt][2][2]);
        float p3 = __builtin_amdgcn_exp2f(s[mt][2][3]);
        asm("v_cvt_pk_bf16_f32 %0, %1, %2" : "=v"(pk4) : "v"(p0), "v"(p1));
        asm("v_cvt_pk_bf16_f32 %0, %1, %2" : "=v"(pk5) : "v"(p2), "v"(p3));
      }
      {
        float p0 = __builtin_amdgcn_exp2f(s[mt][3][0]);
        float p1 = __builtin_amdgcn_exp2f(s[mt][3][1]);
        float p2 = __builtin_amdgcn_exp2f(s[mt][3][2]);
        float p3 = __builtin_amdgcn_exp2f(s[mt][3][3]);
        asm("v_cvt_pk_bf16_f32 %0, %1, %2" : "=v"(pk6) : "v"(p0), "v"(p1));
        asm("v_cvt_pk_bf16_f32 %0, %1, %2" : "=v"(pk7) : "v"(p2), "v"(p3));
      }
      {
        unsigned a0 = pk0, b0 = pk2;
        asm("v_permlane32_swap_b32 %0, %1" : "+v"(a0), "+v"(b0));
        asm("v_permlane16_swap_b32 %0, %1" : "+v"(a0), "+v"(b0));
        unsigned a1 = pk1, b1 = pk3;
        asm("v_permlane32_swap_b32 %0, %1" : "+v"(a1), "+v"(b1));
        asm("v_permlane16_swap_b32 %0, %1" : "+v"(a1), "+v"(b1));
        u32x4 w; w.x = a0; w.y = a1; w.z = b0; w.w = b1;
        ap[mt][0] = __builtin_bit_cast(bf16x8, w);
      }
      {
        unsigned a0 = pk4, b0 = pk6;
        asm("v_permlane32_swap_b32 %0, %1" : "+v"(a0), "+v"(b0));
        asm("v_permlane16_swap_b32 %0, %1" : "+v"(a0), "+v"(b0));
        unsigned a1 = pk5, b1 = pk7;
        asm("v_permlane32_swap_b32 %0, %1" : "+v"(a1), "+v"(b1));
        asm("v_permlane16_swap_b32 %0, %1" : "+v"(a1), "+v"(b1));
        u32x4 w; w.x = a0; w.y = a1; w.z = b0; w.w = b1;
        ap[mt][1] = __builtin_bit_cast(bf16x8, w);
      }
    }

#pragma unroll
    for (int ks = 0; ks < 2; ++ks) {
      bf16x8 bv[4];
#pragma unroll
      for (int dt = 0; dt < 4; ++dt) {
        int row  = dt * 16 + l16;
        int slot = (ks * 4 + q4) ^ (row & 7);
        bv[dt] = *(const bf16x8*)&Vs[row * 64 + slot * 8];
      }
#pragma unroll
      for (int mt = 0; mt < 2; ++mt) {
#pragma unroll
        for (int dt = 0; dt < 4; ++dt)
          o[mt][dt] = __builtin_amdgcn_mfma_f32_16x16x32_bf16(ap[mt][ks], bv[dt],
                                                              o[mt][dt], 0, 0, 0);
        o_l[mt] = __builtin_amdgcn_mfma_f32_16x16x32_bf16(ap[mt][ks], ones_f,
                                                          o_l[mt], 0, 0, 0);
      }
    }
  }

#pragma unroll
  for (int mt = 0; mt < 2; ++mt) {
    float inv[4];
#pragma unroll
    for (int r = 0; r < 4; ++r) {
      float lsum = __shfl(o_l[mt][r], lane & 48);
      inv[r] = 1.0f / lsum;
    }
#pragma unroll
    for (int dt = 0; dt < 4; ++dt)
#pragma unroll
      for (int r = 0; r < 4; ++r) {
        long row = rowbase + wq0 + mt * 16 + q4 * 4 + r;
        int col = h * 64 + dt * 16 + l16;
        outb[row * 2048 + col] = (bf16)(o[mt][dt][r] * inv[r]);
      }
  }
}

// --------------------------------------------------------------------------------
extern "C" void kernel_launch(void* const* d_in, const int* in_sizes, int n_in,
                              void* d_out, int out_size, void* d_ws, size_t ws_size,
                              hipStream_t stream) {
  const float* x   = (const float*)d_in[0];
  const float* wq  = (const float*)d_in[1];
  const float* wkv = (const float*)d_in[2];
  const float* wo  = (const float*)d_in[3];
  float* out = (float*)d_out;
  char* ws = (char*)d_ws;

  // ws layout (bytes):
  //   xbf  [4096*2048] bf16 @ 0          (16,777,216)  -- reused as attn output
  //   w1   [3072*2048] bf16 @ 16777216   (12,582,912)  -- wq^T | wkv^T
  //   qkv  [4096*3072] bf16 @ 29360128   (25,165,824)  -- ends 54,525,952
  //   woT  [2048*2048] bf16 @ 54525952   ( 8,388,608)  -- ends 62,914,560
  //   vT   [2*512*2048] bf16 @ 62914560  ( 4,194,304)  -- ends 67,108,864
  bf16* xbf  = (bf16*)(ws + 0);
  bf16* w1   = (bf16*)(ws + 16777216);
  bf16* qkv  = (bf16*)(ws + 29360128);
  bf16* attn = xbf;              // xbf dead after gemm1

  const bool fused_v  = ws_size >= 67108864u;   // vT slot after woT
  const bool woT_early = ws_size >= 62914560u;

  bf16* woT = woT_early ? (bf16*)(ws + 54525952) : qkv;   // qkv dead after attn
  bf16* vT  = fused_v   ? (bf16*)(ws + 62914560) : w1;    // w1 dead after gemm1

  // fused prep: z=0 cvt(x), z=1 wq^T, z=2 wkv^T, z=3 wo^T (only if early)
  prep_kernel<<<dim3(64, 64, woT_early ? 4 : 3), 256, 0, stream>>>(
      x, xbf, wq, wkv, wo, w1, woT);

  // qkv = [x@wq | x@wkv]; 8-phase 256^2 kernel (grid 12x16 = 192, %8==0)
  if (fused_v) {
    gemm8p_kernel<2048, true, true><<<dim3(12, 16), 512, 0, stream>>>(
        xbf, w1, (void*)qkv, vT, 3072);
  } else {
    gemm8p_kernel<2048, true, false><<<dim3(12, 16), 512, 0, stream>>>(
        xbf, w1, (void*)qkv, nullptr, 3072);
    transpose_v<<<dim3(16, 128), 256, 0, stream>>>(qkv, vT);  // vT = w1 (dead)
  }

  attn_kernel<<<1024, 256, 0, stream>>>(qkv, vT, attn);

  if (!woT_early)
    transpose_cvt<<<dim3(64, 64), 256, 0, stream>>>(wo, woT, 2048, 2048);

  // out = attn @ wo (proven m97-structure kernel)
  gemm_kernel<false, false><<<dim3(16, 32), 256, 0, stream>>>(
      attn, woT, (void*)out, nullptr, 2048, 2048);
}

// Round 13
// 254.666 us; speedup vs baseline: 1.0780x; 1.0780x over previous
//
#include <hip/hip_runtime.h>

using bf16   = __bf16;
using bf16x8 = __attribute__((ext_vector_type(8))) __bf16;
using f32x4  = __attribute__((ext_vector_type(4))) float;
using u32x4  = __attribute__((ext_vector_type(4))) unsigned;

// B=2 T=2048 D=2048 H=32 KVH=8 HD=64 GROUPS=4 ; M=B*T=4096 ; NQKV=3072
#define T_SEQ 2048
#define NQKV 3072

__device__ __forceinline__ void async_cp16(const bf16* g, bf16* l) {
  __builtin_amdgcn_global_load_lds((__attribute__((address_space(1))) void*)(void*)g,
                                   (__attribute__((address_space(3))) void*)l, 16, 0, 0);
}

// ------------- fused prep: cvt(x) | wq^T | wkv^T | wo^T as z-slices -------------
__global__ __launch_bounds__(256) void prep_kernel(
    const float* __restrict__ x, bf16* __restrict__ xbf,
    const float* __restrict__ wq, const float* __restrict__ wkv,
    const float* __restrict__ wo, bf16* __restrict__ w1,
    bf16* __restrict__ woT) {
  const int z = blockIdx.z;
  if (z == 0) {                 // fp32 -> bf16 convert of x (64x64 blocks = 4096)
    long i = (((long)blockIdx.y * 64 + blockIdx.x) * 256 + threadIdx.x) * 8;
    float4 a = *(const float4*)(x + i);
    float4 c = *(const float4*)(x + i + 4);
    bf16x8 v;
    v[0] = (bf16)a.x; v[1] = (bf16)a.y; v[2] = (bf16)a.z; v[3] = (bf16)a.w;
    v[4] = (bf16)c.x; v[5] = (bf16)c.y; v[6] = (bf16)c.z; v[7] = (bf16)c.w;
    *(bf16x8*)(xbf + i) = v;
    return;
  }
  const float* in; bf16* out; int R, C;
  if (z == 1)      { in = wq;  out = w1;                R = 2048; C = 2048; }
  else if (z == 2) { if (blockIdx.x >= 32) return;
                     in = wkv; out = w1 + 2048L * 2048; R = 2048; C = 1024; }
  else             { in = wo;  out = woT;               R = 2048; C = 2048; }
  __shared__ float tile[32][33];
  const int tc = blockIdx.x * 32;
  const int tr = blockIdx.y * 32;
  const int t = threadIdx.x;
  const int lr = t >> 5;
  const int lc = t & 31;
#pragma unroll
  for (int i = 0; i < 4; ++i)
    tile[lr + i * 8][lc] = in[(size_t)(tr + lr + i * 8) * C + tc + lc];
  __syncthreads();
#pragma unroll
  for (int i = 0; i < 4; ++i)
    out[(size_t)(tc + lr + i * 8) * R + tr + lc] = (bf16)tile[lc][lr + i * 8];
}

// ------------- transpose + convert (standalone, fallback paths) ----------------
__global__ __launch_bounds__(256) void transpose_cvt(const float* __restrict__ in,
                                                     bf16* __restrict__ out,
                                                     int R, int C) {
  __shared__ float tile[32][33];
  const int tc = blockIdx.x * 32;
  const int tr = blockIdx.y * 32;
  const int t = threadIdx.x;
  const int lr = t >> 5;
  const int lc = t & 31;
#pragma unroll
  for (int i = 0; i < 4; ++i)
    tile[lr + i * 8][lc] = in[(size_t)(tr + lr + i * 8) * C + tc + lc];
  __syncthreads();
#pragma unroll
  for (int i = 0; i < 4; ++i)
    out[(size_t)(tc + lr + i * 8) * R + tr + lc] = (bf16)tile[lc][lr + i * 8];
}

// ------------- bf16 transpose of the V block of qkv (fallback path) -------------
__global__ __launch_bounds__(256) void transpose_v(const bf16* __restrict__ in,
                                                   bf16* __restrict__ out) {
  __shared__ bf16 tile[32][33];
  const int c0 = blockIdx.x * 32;   // 0..480
  const int r0 = blockIdx.y * 32;   // 0..4064
  const int t = threadIdx.x;
  const int lr = t >> 5;
  const int lc = t & 31;
#pragma unroll
  for (int i = 0; i < 4; ++i)
    tile[lr + i * 8][lc] = in[(size_t)(r0 + lr + i * 8) * NQKV + 2560 + c0 + lc];
  __syncthreads();
#pragma unroll
  for (int i = 0; i < 4; ++i) {
    int c = c0 + lr + i * 8;
    int r = r0 + lc;
    out[(size_t)((r >> 11) * 512 + c) * 2048 + (r & 2047)] = tile[lc][lr + i * 8];
  }
}

// ------------- GEMM: C[M][N] = A[M][K] * Bt[N][K]^T  (bf16 in, fp32 acc) --------
// r20 = r8-exact (the measured-best 245.2us config). 8-phase line permanently
// closed: three independent ports (r12 60.5 / r13 70.1 / r19 88.8us) all lost
// to this 2-barrier m97 structure (55-56us, 937 TF) at this problem size.
template <bool OUT_BF16, bool V_SPLIT>
__global__ __launch_bounds__(256, 4)
void gemm_kernel(const bf16* __restrict__ A, const bf16* __restrict__ Bt,
                 void* __restrict__ Cout, bf16* __restrict__ vTout,
                 int Kdim, int Ndim) {
  __shared__ __attribute__((aligned(16))) bf16 As[128 * 64];
  __shared__ __attribute__((aligned(16))) bf16 Bs[128 * 64];
  const int tid  = threadIdx.x;
  const int lane = tid & 63;
  const int wave = tid >> 6;
  const int l16  = lane & 15;
  const int q4   = lane >> 4;
  const long m0 = (long)blockIdx.y * 128;
  const long n0 = (long)blockIdx.x * 128;
  const int wm = (wave >> 1) * 64;
  const int wn = (wave & 1) * 64;

  f32x4 acc[4][4] = {};

  for (int k0 = 0; k0 < Kdim; k0 += 64) {
    __syncthreads();
#pragma unroll
    for (int rr = 0; rr < 4; ++rr) {
      int ci  = rr * 256 + tid;     // 16B chunk index 0..1023
      int row = ci >> 3;
      int chp = ci & 7;             // swizzled LDS chunk slot
      int ch  = chp ^ (row & 7);    // global chunk
      async_cp16(A + (m0 + row) * (long)Kdim + k0 + ch * 8, &As[ci * 8]);
      async_cp16(Bt + (n0 + row) * (long)Kdim + k0 + ch * 8, &Bs[ci * 8]);
    }
    __syncthreads();
#pragma unroll
    for (int ks = 0; ks < 2; ++ks) {
      bf16x8 af[4], bfr[4];
#pragma unroll
      for (int mt = 0; mt < 4; ++mt) {
        int row = wm + mt * 16 + l16;
        int chp = (ks * 4 + q4) ^ (row & 7);
        af[mt] = *(const bf16x8*)&As[row * 64 + chp * 8];
      }
#pragma unroll
      for (int nt = 0; nt < 4; ++nt) {
        int row = wn + nt * 16 + l16;
        int chp = (ks * 4 + q4) ^ (row & 7);
        bfr[nt] = *(const bf16x8*)&Bs[row * 64 + chp * 8];
      }
#pragma unroll
      for (int mt = 0; mt < 4; ++mt)
#pragma unroll
        for (int nt = 0; nt < 4; ++nt)
          acc[mt][nt] = __builtin_amdgcn_mfma_f32_16x16x32_bf16(af[mt], bfr[nt],
                                                                acc[mt][nt], 0, 0, 0);
    }
  }

  if constexpr (V_SPLIT) {
    if (n0 >= 2560) {   // V block: write transposed directly to vT
#pragma unroll
      for (int mt = 0; mt < 4; ++mt)
#pragma unroll
        for (int nt = 0; nt < 4; ++nt)
#pragma unroll
          for (int r = 0; r < 4; ++r) {
            long row = m0 + wm + mt * 16 + q4 * 4 + r;
            long c   = n0 + wn + nt * 16 + l16 - 2560;
            vTout[((row >> 11) * 512 + c) * 2048 + (row & 2047)] =
                (bf16)acc[mt][nt][r];
          }
      return;
    }
  }
#pragma unroll
  for (int mt = 0; mt < 4; ++mt)
#pragma unroll
    for (int nt = 0; nt < 4; ++nt)
#pragma unroll
      for (int r = 0; r < 4; ++r) {
        long row = m0 + wm + mt * 16 + q4 * 4 + r;
        long col = n0 + wn + nt * 16 + l16;
        float v = acc[mt][nt][r];
        if constexpr (OUT_BF16)
          ((bf16*)Cout)[row * Ndim + col] = (bf16)v;
        else
          ((float*)Cout)[row * Ndim + col] = v;
      }
}

// ------------- causal GQA flash attention ---------------------------------------
// r20 on top of the r8 attn (the 245.2us config): DOUBLE-BUFFERED K/V LDS,
// one __syncthreads per kv-tile instead of two. Safety: iter t writes buf[t&1];
// laggards read buf[(t-1)&1] (other buffer). A wave reaching iter t+2's write
// of buf[cur] has passed iter t+1's barrier => all waves finished iter t's
// reads of buf[cur]. Write -> barrier -> compute preserves visibility.
// LDS 16 -> 32 KB (still 3 blocks/CU); registers unchanged (kr/vr[2] - the
// 3/3 spill pattern forbids growing the live set).
__global__ __launch_bounds__(256, 3)
void attn_kernel(const bf16* __restrict__ qkv, const bf16* __restrict__ vT,
                 bf16* __restrict__ outb) {
  __shared__ __attribute__((aligned(16))) bf16 Ks[2][64 * 64];
  __shared__ __attribute__((aligned(16))) bf16 Vs[2][64 * 64];

  const int tid  = threadIdx.x;
  const int lane = tid & 63;
  const int wave = tid >> 6;
  const int l16  = lane & 15;
  const int q4   = lane >> 4;

  const int bid = blockIdx.x;
  const int qt  = 15 - (bid >> 6);   // heavy q-tiles dispatched first
  const int bh  = bid & 63;
  const int b   = bh >> 5;
  const int h   = bh & 31;
  const int kvh = h >> 2;
  const long rowbase = (long)b * T_SEQ;

  const int qrow0 = qt * 128;
  const int wq0   = qrow0 + wave * 32;
  const float cexp = 0.125f * 1.4426950408889634f;  // scale * log2(e), folded into Q

  // Q fragments in registers, pre-scaled by cexp (so P = exp2(S) directly)
  bf16x8 aq[2][2];
#pragma unroll
  for (int mt = 0; mt < 2; ++mt)
#pragma unroll
    for (int ks = 0; ks < 2; ++ks) {
      bf16x8 v = *(const bf16x8*)(qkv +
          (rowbase + wq0 + mt * 16 + l16) * (long)NQKV + h * 64 + ks * 32 + q4 * 8);
#pragma unroll
      for (int i = 0; i < 8; ++i) v[i] = (bf16)((float)v[i] * cexp);
      aq[mt][ks] = v;
    }

  // ones B-fragment: B[k][n=0]=1 -> accumulates row-sums of P into col 0
  bf16x8 ones_f;
#pragma unroll
  for (int i = 0; i < 8; ++i) ones_f[i] = (l16 == 0) ? (bf16)1.0f : (bf16)0.0f;

  f32x4 o[2][4] = {};
  f32x4 o_l[2] = {};

  const bf16* kbase = qkv + rowbase * (long)NQKV + 2048 + kvh * 64;
  const bf16* vbase = vT + ((long)b * 512 + kvh * 64) * 2048;

  const int ntiles = (qrow0 + 128) >> 6;

  // T14 prologue: tile 0 -> regs
  bf16x8 kr[2], vr[2];
#pragma unroll
  for (int h2 = 0; h2 < 2; ++h2) {
    int ci = h2 * 256 + tid, row = ci >> 3, ch = (ci & 7) ^ (row & 7);
    kr[h2] = *(const bf16x8*)(kbase + (long)row * NQKV + ch * 8);
    vr[h2] = *(const bf16x8*)(vbase + (long)row * 2048 + ch * 8);
  }

  for (int t = 0; t < ntiles; ++t) {
    const int j0 = t * 64;
    const int cur = t & 1;
#pragma unroll
    for (int h2 = 0; h2 < 2; ++h2) {     // regs -> LDS buf[cur] (other buf in use)
      int ci = h2 * 256 + tid;
      *(bf16x8*)&Ks[cur][ci * 8] = kr[h2];
      *(bf16x8*)&Vs[cur][ci * 8] = vr[h2];
    }
    __syncthreads();                     // writes visible; prior-parity reads done
    if (t + 1 < ntiles) {                // issue next tile's loads; land during compute
      const int jn = j0 + 64;
#pragma unroll
      for (int h2 = 0; h2 < 2; ++h2) {
        int ci = h2 * 256 + tid, row = ci >> 3, ch = (ci & 7) ^ (row & 7);
        kr[h2] = *(const bf16x8*)(kbase + (long)(jn + row) * NQKV + ch * 8);
        vr[h2] = *(const bf16x8*)(vbase + (long)row * 2048 + jn + ch * 8);
      }
    }
    if (j0 > wq0 + 31) continue;   // tile entirely above diagonal for this wave

    // S^T = K Q^T  (operand-swapped: tiles [kv = nt][q = mt])
    f32x4 s[2][4] = {};
#pragma unroll
    for (int ks = 0; ks < 2; ++ks) {
      bf16x8 bk[4];
#pragma unroll
      for (int nt = 0; nt < 4; ++nt) {
        int row  = nt * 16 + l16;
        int slot = (ks * 4 + q4) ^ (row & 7);
        bk[nt] = *(const bf16x8*)&Ks[cur][row * 64 + slot * 8];
      }
#pragma unroll
      for (int mt = 0; mt < 2; ++mt)
#pragma unroll
        for (int nt = 0; nt < 4; ++nt)
          s[mt][nt] = __builtin_amdgcn_mfma_f32_16x16x32_bf16(bk[nt], aq[mt][ks],
                                                              s[mt][nt], 0, 0, 0);
    }

    if (j0 + 63 > wq0) {   // diagonal tile: causal mask (S^T: row=kv, col=q)
#pragma unroll
      for (int mt = 0; mt < 2; ++mt)
#pragma unroll
        for (int nt = 0; nt < 4; ++nt)
#pragma unroll
          for (int r = 0; r < 4; ++r) {
            int rg = wq0 + mt * 16 + l16;          // q row
            int cg = j0 + nt * 16 + q4 * 4 + r;    // kv col
            if (cg > rg) s[mt][nt][r] = -__builtin_inff();
          }
    }

    // P = exp2(S^T) via bare v_exp_f32; pack pairs with v_cvt_pk_bf16_f32;
    // route packed words into PV A-fragments with permlane32/16_swap.
    bf16x8 ap[2][2];
#pragma unroll
    for (int mt = 0; mt < 2; ++mt) {
      unsigned pk0, pk1, pk2, pk3, pk4, pk5, pk6, pk7;  // pk[nt][j], named scalars
      {
        float p0 = __builtin_amdgcn_exp2f(s[mt][0][0]);
        float p1 = __builtin_amdgcn_exp2f(s[mt][0][1]);
        float p2 = __builtin_amdgcn_exp2f(s[mt][0][2]);
        float p3 = __builtin_amdgcn_exp2f(s[mt][0][3]);
        asm("v_cvt_pk_bf16_f32 %0, %1, %2" : "=v"(pk0) : "v"(p0), "v"(p1));
        asm("v_cvt_pk_bf16_f32 %0, %1, %2" : "=v"(pk1) : "v"(p2), "v"(p3));
      }
      {
        float p0 = __builtin_amdgcn_exp2f(s[mt][1][0]);
        float p1 = __builtin_amdgcn_exp2f(s[mt][1][1]);
        float p2 = __builtin_amdgcn_exp2f(s[mt][1][2]);
        float p3 = __builtin_amdgcn_exp2f(s[mt][1][3]);
        asm("v_cvt_pk_bf16_f32 %0, %1, %2" : "=v"(pk2) : "v"(p0), "v"(p1));
        asm("v_cvt_pk_bf16_f32 %0, %1, %2" : "=v"(pk3) : "v"(p2), "v"(p3));
      }
      {
        float p0 = __builtin_amdgcn_exp2f(s[mt][2][0]);
        float p1 = __builtin_amdgcn_exp2f(s[mt][2][1]);
        float p2 = __builtin_amdgcn_exp2f(s[mt][2][2]);
        float p3 = __builtin_amdgcn_exp2f(s[mt][2][3]);
        asm("v_cvt_pk_bf16_f32 %0, %1, %2" : "=v"(pk4) : "v"(p0), "v"(p1));
        asm("v_cvt_pk_bf16_f32 %0, %1, %2" : "=v"(pk5) : "v"(p2), "v"(p3));
      }
      {
        float p0 = __builtin_amdgcn_exp2f(s[mt][3][0]);
        float p1 = __builtin_amdgcn_exp2f(s[mt][3][1]);
        float p2 = __builtin_amdgcn_exp2f(s[mt][3][2]);
        float p3 = __builtin_amdgcn_exp2f(s[mt][3][3]);
        asm("v_cvt_pk_bf16_f32 %0, %1, %2" : "=v"(pk6) : "v"(p0), "v"(p1));
        asm("v_cvt_pk_bf16_f32 %0, %1, %2" : "=v"(pk7) : "v"(p2), "v"(p3));
      }
      // ks = 0: sources pk[0][*], pk[1][*]
      {
        unsigned a0 = pk0, b0 = pk2;
        asm("v_permlane32_swap_b32 %0, %1" : "+v"(a0), "+v"(b0));
        asm("v_permlane16_swap_b32 %0, %1" : "+v"(a0), "+v"(b0));
        unsigned a1 = pk1, b1 = pk3;
        asm("v_permlane32_swap_b32 %0, %1" : "+v"(a1), "+v"(b1));
        asm("v_permlane16_swap_b32 %0, %1" : "+v"(a1), "+v"(b1));
        u32x4 w; w.x = a0; w.y = a1; w.z = b0; w.w = b1;
        ap[mt][0] = __builtin_bit_cast(bf16x8, w);
      }
      // ks = 1: sources pk[2][*], pk[3][*]
      {
        unsigned a0 = pk4, b0 = pk6;
        asm("v_permlane32_swap_b32 %0, %1" : "+v"(a0), "+v"(b0));
        asm("v_permlane16_swap_b32 %0, %1" : "+v"(a0), "+v"(b0));
        unsigned a1 = pk5, b1 = pk7;
        asm("v_permlane32_swap_b32 %0, %1" : "+v"(a1), "+v"(b1));
        asm("v_permlane16_swap_b32 %0, %1" : "+v"(a1), "+v"(b1));
        u32x4 w; w.x = a0; w.y = a1; w.z = b0; w.w = b1;
        ap[mt][1] = __builtin_bit_cast(bf16x8, w);
      }
    }

    // O += P V ; ell += P 1
#pragma unroll
    for (int ks = 0; ks < 2; ++ks) {
      bf16x8 bv[4];
#pragma unroll
      for (int dt = 0; dt < 4; ++dt) {
        int row  = dt * 16 + l16;
        int slot = (ks * 4 + q4) ^ (row & 7);
        bv[dt] = *(const bf16x8*)&Vs[cur][row * 64 + slot * 8];
      }
#pragma unroll
      for (int mt = 0; mt < 2; ++mt) {
#pragma unroll
        for (int dt = 0; dt < 4; ++dt)
          o[mt][dt] = __builtin_amdgcn_mfma_f32_16x16x32_bf16(ap[mt][ks], bv[dt],
                                                              o[mt][dt], 0, 0, 0);
        o_l[mt] = __builtin_amdgcn_mfma_f32_16x16x32_bf16(ap[mt][ks], ones_f,
                                                          o_l[mt], 0, 0, 0);
      }
    }
  }

  // epilogue: normalize (row-sum broadcast from col-0 lane) and store bf16
#pragma unroll
  for (int mt = 0; mt < 2; ++mt) {
    float inv[4];
#pragma unroll
    for (int r = 0; r < 4; ++r) {
      float lsum = __shfl(o_l[mt][r], lane & 48);   // lane q4*16 holds col 0
      inv[r] = 1.0f / lsum;
    }
#pragma unroll
    for (int dt = 0; dt < 4; ++dt)
#pragma unroll
      for (int r = 0; r < 4; ++r) {
        long row = rowbase + wq0 + mt * 16 + q4 * 4 + r;
        int col = h * 64 + dt * 16 + l16;
        outb[row * 2048 + col] = (bf16)(o[mt][dt][r] * inv[r]);
      }
  }
}

// --------------------------------------------------------------------------------
extern "C" void kernel_launch(void* const* d_in, const int* in_sizes, int n_in,
                              void* d_out, int out_size, void* d_ws, size_t ws_size,
                              hipStream_t stream) {
  const float* x   = (const float*)d_in[0];
  const float* wq  = (const float*)d_in[1];
  const float* wkv = (const float*)d_in[2];
  const float* wo  = (const float*)d_in[3];
  float* out = (float*)d_out;
  char* ws = (char*)d_ws;

  // ws layout (bytes):
  //   xbf  [4096*2048] bf16 @ 0          (16,777,216)  -- reused as attn output
  //   w1   [3072*2048] bf16 @ 16777216   (12,582,912)  -- wq^T | wkv^T
  //   qkv  [4096*3072] bf16 @ 29360128   (25,165,824)  -- ends 54,525,952
  //   woT  [2048*2048] bf16 @ 54525952   ( 8,388,608)  -- ends 62,914,560
  //   vT   [2*512*2048] bf16 @ 62914560  ( 4,194,304)  -- ends 67,108,864
  bf16* xbf  = (bf16*)(ws + 0);
  bf16* w1   = (bf16*)(ws + 16777216);
  bf16* qkv  = (bf16*)(ws + 29360128);
  bf16* attn = xbf;              // xbf dead after gemm1

  const bool fused_v  = ws_size >= 67108864u;   // vT slot after woT
  const bool woT_early = ws_size >= 62914560u;

  bf16* woT = woT_early ? (bf16*)(ws + 54525952) : qkv;   // qkv dead after attn
  bf16* vT  = fused_v   ? (bf16*)(ws + 62914560) : w1;    // w1 dead after gemm1

  // fused prep: z=0 cvt(x), z=1 wq^T, z=2 wkv^T, z=3 wo^T (only if early)
  prep_kernel<<<dim3(64, 64, woT_early ? 4 : 3), 256, 0, stream>>>(
      x, xbf, wq, wkv, wo, w1, woT);

  // qkv = [x@wq | x@wkv]; fused path also writes V directly to vT (transposed)
  if (fused_v) {
    gemm_kernel<true, true><<<dim3(24, 32), 256, 0, stream>>>(
        xbf, w1, (void*)qkv, vT, 2048, 3072);
  } else {
    gemm_kernel<true, false><<<dim3(24, 32), 256, 0, stream>>>(
        xbf, w1, (void*)qkv, nullptr, 2048, 3072);
    transpose_v<<<dim3(16, 128), 256, 0, stream>>>(qkv, vT);  // vT = w1 (dead)
  }

  attn_kernel<<<1024, 256, 0, stream>>>(qkv, vT, attn);

  if (!woT_early)
    transpose_cvt<<<dim3(64, 64), 256, 0, stream>>>(wo, woT, 2048, 2048);

  // out = attn @ wo
  gemm_kernel<false, false><<<dim3(16, 32), 256, 0, stream>>>(
      attn, woT, (void*)out, nullptr, 2048, 2048);
}